// Round 3
// baseline (289.930 us; speedup 1.0000x reference)
//
#include <hip/hip_runtime.h>
#include <hip/hip_bf16.h>

// Problem constants: B=8, S=2048, E=768, HEAD=128
#define BB 8
#define SS 2048
#define EE 768
#define HH 128
#define MM (BB*SS)     // 16384
#define NQT 32         // 64-row q-tiles per batch
#define NCH 144        // chunks per batch: sum_{qt} ceil((qt+1)/4)

typedef __attribute__((ext_vector_type(8))) short bf16x8;
typedef __attribute__((ext_vector_type(4))) float f32x4;

__device__ __forceinline__ unsigned short f2bf(float x) {
    unsigned int u = __float_as_uint(x);
    u += 0x7fff + ((u >> 16) & 1);   // RNE
    return (unsigned short)(u >> 16);
}
__device__ __forceinline__ float bf2f(unsigned short h) {
    return __uint_as_float(((unsigned int)h) << 16);
}
// async global->LDS, 16B per lane; LDS dest = wave-uniform base + lane*16
__device__ __forceinline__ void gld16(const unsigned short* g, unsigned short* l) {
    __builtin_amdgcn_global_load_lds(
        (const __attribute__((address_space(1))) unsigned int*)g,
        (__attribute__((address_space(3))) unsigned int*)l, 16, 0, 0);
}

// ---------------------------------------------------------------------------
// cvt: Xb = bf16(X * mask)  [16384][768];  Wb = bf16([Wq;Wk;Wv]) [384][768]
// grid 12288 + 288 blocks, 256 thr
// ---------------------------------------------------------------------------
__global__ __launch_bounds__(256)
void cvt(const float* __restrict__ X, const float* __restrict__ mask,
         const float* __restrict__ Wq, const float* __restrict__ Wk,
         const float* __restrict__ Wv,
         unsigned short* __restrict__ Xb, unsigned short* __restrict__ Wb)
{
    if (blockIdx.x < 12288) {
        size_t i4 = ((size_t)blockIdx.x * 256 + threadIdx.x) * 4;
        int row = (int)(i4 / EE);
        float mk = mask[row];
        float4 v = *(const float4*)(X + i4);
        ushort4 o;
        o.x = f2bf(v.x * mk); o.y = f2bf(v.y * mk);
        o.z = f2bf(v.z * mk); o.w = f2bf(v.w * mk);
        *(ushort4*)(Xb + i4) = o;
    } else {
        int i4 = ((blockIdx.x - 12288) * 256 + threadIdx.x) * 4;   // < 294912
        const float* src; int off;
        if (i4 < 98304)       { src = Wq; off = i4; }
        else if (i4 < 196608) { src = Wk; off = i4 - 98304; }
        else                  { src = Wv; off = i4 - 196608; }
        float4 v = *(const float4*)(src + off);
        ushort4 o;
        o.x = f2bf(v.x); o.y = f2bf(v.y); o.z = f2bf(v.z); o.w = f2bf(v.w);
        *(ushort4*)(Wb + i4) = o;
    }
}

// ---------------------------------------------------------------------------
// QKV GEMM: 128Mx128N tile, BK=64, grid (128, 3), 4 waves 2x2 of 64x64.
// global_load_lds(16B) staging, xor-swizzled unpadded LDS (conflict-free).
// mat 2 (V) epilogue: LDS-bounce transpose -> coalesced Vt[h][token] stores.
// ---------------------------------------------------------------------------
__global__ __launch_bounds__(256, 2)
void qkv_gemm(const unsigned short* __restrict__ Xb, const unsigned short* __restrict__ Wb,
              unsigned short* __restrict__ Q, unsigned short* __restrict__ K,
              unsigned short* __restrict__ Vt)
{
    const int m0  = blockIdx.x * 128;
    const int mat = blockIdx.y;
    const int n0g = mat * 128;               // row offset into Wb [384][768]

    __shared__ __align__(16) unsigned short SM[16384];   // As[0:8192) Bs[8192:16384)
    unsigned short* As = SM;
    unsigned short* Bs = SM + 8192;

    const int t = threadIdx.x, lane = t & 63;
    const int quad = lane >> 4, l16 = lane & 15;
    const int wave = t >> 6;
    const int wm = (wave >> 1) * 64, wn = (wave & 1) * 64;
    const int wub = (t & 192) * 8;           // wave-uniform chunk base *8 shorts

    f32x4 acc[4][4];
#pragma unroll
    for (int i = 0; i < 4; i++)
#pragma unroll
        for (int j = 0; j < 4; j++) acc[i][j] = (f32x4)0.0f;

    for (int k0 = 0; k0 < EE; k0 += 64) {
        __syncthreads();
        // A/B tiles: 128 rows x 8 chunks(16B). slot = c ^ (row&7).
#pragma unroll
        for (int i = 0; i < 4; i++) {
            int cg = i * 256 + t;
            int row = cg >> 3, slot = cg & 7;
            int cc = slot ^ (row & 7);
            gld16(Xb + (size_t)(m0 + row) * EE + k0 + cc * 8, As + i * 2048 + wub);
            gld16(Wb + (size_t)(n0g + row) * EE + k0 + cc * 8, Bs + i * 2048 + wub);
        }
        __syncthreads();
#pragma unroll
        for (int kk = 0; kk < 2; kk++) {
            bf16x8 a[4], b[4];
#pragma unroll
            for (int i = 0; i < 4; i++) {
                int row = wm + i * 16 + l16;
                a[i] = *(const bf16x8*)&As[row * 64 + (((kk * 4 + quad) ^ (l16 & 7)) << 3)];
            }
#pragma unroll
            for (int j = 0; j < 4; j++) {
                int row = wn + j * 16 + l16;
                b[j] = *(const bf16x8*)&Bs[row * 64 + (((kk * 4 + quad) ^ (l16 & 7)) << 3)];
            }
#pragma unroll
            for (int i = 0; i < 4; i++)
#pragma unroll
                for (int j = 0; j < 4; j++)
                    acc[i][j] = __builtin_amdgcn_mfma_f32_16x16x32_bf16(a[i], b[j], acc[i][j], 0, 0, 0);
        }
    }

    if (mat < 2) {
        unsigned short* dst = (mat == 0) ? Q : K;
#pragma unroll
        for (int i = 0; i < 4; i++)
#pragma unroll
            for (int r = 0; r < 4; r++) {
                int m = m0 + wm + i * 16 + quad * 4 + r;
#pragma unroll
                for (int j = 0; j < 4; j++)
                    dst[(size_t)m * HH + wn + j * 16 + l16] = f2bf(acc[i][j][r]);
            }
    } else {
        // transpose 128(tok) x 128(h) through LDS, swizzle slot = c ^ (h&15)
        __syncthreads();
#pragma unroll
        for (int i = 0; i < 4; i++)
#pragma unroll
            for (int r = 0; r < 4; r++) {
                int tok = wm + i * 16 + quad * 4 + r;
                int cc = tok >> 3, w = tok & 7;
#pragma unroll
                for (int j = 0; j < 4; j++) {
                    int h = wn + j * 16 + l16;
                    SM[h * 128 + ((cc ^ (h & 15)) << 3) + w] = f2bf(acc[i][j][r]);
                }
            }
        __syncthreads();
        const int bidx = m0 >> 11, mloc = m0 & 2047;
#pragma unroll
        for (int it = 0; it < 8; it++) {
            int cg = it * 256 + t;
            int h = cg >> 4, cc = cg & 15;
            ulonglong2 v = *(const ulonglong2*)&SM[h * 128 + ((cc ^ (h & 15)) << 3)];
            *(ulonglong2*)&Vt[((size_t)bidx * HH + h) * SS + mloc + cc * 8] = v;
        }
    }
}

// ---------------------------------------------------------------------------
// Flash attention, balanced chunked k-split: chunk id c in [0,144) per batch.
// qt group g = qt>>2 has g+1 chunks of <=4 k-tiles each (contiguous).
// LDS: Ks 16K + Vs 16K + Ps 8K = 40KB -> 4 blocks/CU. All xor-swizzled.
// grid (144, 8), block 256 (4 waves of 16 q-rows)
// ---------------------------------------------------------------------------
__global__ __launch_bounds__(256, 4)
void attn(const unsigned short* __restrict__ Q, const unsigned short* __restrict__ K,
          const unsigned short* __restrict__ Vt,
          unsigned short* __restrict__ Po, float* __restrict__ Pm, float* __restrict__ Pl)
{
    const int b = blockIdx.y;
    const int c = blockIdx.x;
    // decode chunk id -> (qt, ch):  cumulative chunks before group g = 2g(g+1)
    int g = (int)((__builtin_sqrtf(2.0f * c + 1.0f) - 1.0f) * 0.5f);
    while (2 * (g + 1) * (g + 2) <= c) g++;
    while (2 * g * (g + 1) > c) g--;
    const int idx = c - 2 * g * (g + 1);
    const int qt = 4 * g + idx / (g + 1);
    const int ch = idx % (g + 1);
    const int q0 = qt * 64;
    const int kt0 = ch * 4;
    const int kt1 = min(kt0 + 4, qt + 1);

    const int t = threadIdx.x, lane = t & 63;
    const int wave = t >> 6, quad = lane >> 4, l16 = lane & 15;
    const int wub = (t & 192) * 8;

    __shared__ __align__(16) unsigned short Ks[64 * 128];   // [tok][d], slot=c^ (tok&15)
    __shared__ __align__(16) unsigned short Vs[128 * 64];   // [h][tok], slot=c^(h&7)
    __shared__ __align__(16) unsigned short Ps[4][16 * 64]; // per-wave, slot=c^(row&7)

    bf16x8 qf[4];
    {
        const unsigned short* qrow = Q + (size_t)(b * SS + q0 + wave * 16 + l16) * HH;
#pragma unroll
        for (int dd = 0; dd < 4; dd++)
            qf[dd] = *(const bf16x8*)(qrow + dd * 32 + quad * 8);
    }

    f32x4 o[8];
#pragma unroll
    for (int j = 0; j < 8; j++) o[j] = (f32x4)0.0f;
    f32x4 o9 = (f32x4)0.0f;
    float mrow[4];
#pragma unroll
    for (int r = 0; r < 4; r++) mrow[r] = -1e30f;

    const float sscale = 0.08838834764831845f * 1.4426950408889634f;

    bf16x8 ones;
    {
        short e = (l16 == 0) ? (short)0x3F80 : (short)0;
        ones = (bf16x8){e, e, e, e, e, e, e, e};
    }

    for (int kt = kt0; kt < kt1; kt++) {
        const int k0 = kt * 64;
        __syncthreads();
        // K-tile: 64 rows x 16 chunks
#pragma unroll
        for (int i = 0; i < 4; i++) {
            int cg = i * 256 + t;
            int row = cg >> 4, slot = cg & 15;
            int cc = slot ^ (row & 15);
            gld16(K + (size_t)(b * SS + k0 + row) * HH + cc * 8, Ks + i * 2048 + wub);
        }
        // V-tile: 128 rows x 8 chunks
#pragma unroll
        for (int i = 0; i < 4; i++) {
            int cg = i * 256 + t;
            int row = cg >> 3, slot = cg & 7;
            int cc = slot ^ (row & 7);
            gld16(Vt + ((size_t)b * HH + row) * SS + k0 + cc * 8, Vs + i * 2048 + wub);
        }
        __syncthreads();

        // S = Q K^T
        f32x4 s[4];
#pragma unroll
        for (int ct = 0; ct < 4; ct++) s[ct] = (f32x4)0.0f;
#pragma unroll
        for (int dd = 0; dd < 4; dd++) {
#pragma unroll
            for (int ct = 0; ct < 4; ct++) {
                bf16x8 kfr = *(const bf16x8*)&Ks[(ct * 16 + l16) * 128 + (((dd * 4 + quad) ^ l16) << 3)];
                s[ct] = __builtin_amdgcn_mfma_f32_16x16x32_bf16(qf[dd], kfr, s[ct], 0, 0, 0);
            }
        }

        const bool diag = (kt == qt);
        float sv[4][4];
#pragma unroll
        for (int ct = 0; ct < 4; ct++) {
            int col = k0 + ct * 16 + l16;
#pragma unroll
            for (int r = 0; r < 4; r++) {
                float v = s[ct][r] * sscale;
                if (diag) {
                    int row = q0 + wave * 16 + quad * 4 + r;
                    if (col > row) v = -1e30f;
                }
                sv[ct][r] = v;
            }
        }

        float alpha[4];
#pragma unroll
        for (int r = 0; r < 4; r++) {
            float v = fmaxf(fmaxf(sv[0][r], sv[1][r]), fmaxf(sv[2][r], sv[3][r]));
            v = fmaxf(v, __shfl_xor(v, 1));
            v = fmaxf(v, __shfl_xor(v, 2));
            v = fmaxf(v, __shfl_xor(v, 4));
            v = fmaxf(v, __shfl_xor(v, 8));
            float mnew = fmaxf(mrow[r], v);
            alpha[r] = exp2f(mrow[r] - mnew);
            mrow[r]  = mnew;
        }
        // P -> wave-private swizzled LDS (row = quad*4+r, col = ct*16+l16)
#pragma unroll
        for (int ct = 0; ct < 4; ct++) {
#pragma unroll
            for (int r = 0; r < 4; r++) {
                float p = exp2f(sv[ct][r] - mrow[r]);
                int row = quad * 4 + r, col = ct * 16 + l16;
                int cc = col >> 3;
                Ps[wave][row * 64 + (((cc ^ (row & 7)) << 3) | (col & 7))] = f2bf(p);
            }
        }
#pragma unroll
        for (int j = 0; j < 8; j++)
#pragma unroll
            for (int r = 0; r < 4; r++) o[j][r] *= alpha[r];
#pragma unroll
        for (int r = 0; r < 4; r++) o9[r] *= alpha[r];

        // PV + row-sum column
#pragma unroll
        for (int kk = 0; kk < 2; kk++) {
            bf16x8 pf = *(const bf16x8*)&Ps[wave][l16 * 64 + (((kk * 4 + quad) ^ (l16 & 7)) << 3)];
#pragma unroll
            for (int j = 0; j < 8; j++) {
                bf16x8 vf = *(const bf16x8*)&Vs[(j * 16 + l16) * 64 + (((kk * 4 + quad) ^ (l16 & 7)) << 3)];
                o[j] = __builtin_amdgcn_mfma_f32_16x16x32_bf16(pf, vf, o[j], 0, 0, 0);
            }
            o9 = __builtin_amdgcn_mfma_f32_16x16x32_bf16(pf, ones, o9, 0, 0, 0);
        }
    }

    const size_t pidx = (size_t)b * NCH + c;
    const size_t pobase = pidx * (64 * 128);
    const size_t mbase  = pidx * 64;
#pragma unroll
    for (int r = 0; r < 4; r++) {
        int row = wave * 16 + quad * 4 + r;
        if (l16 == 0) { Pm[mbase + row] = mrow[r]; Pl[mbase + row] = o9[r]; }
#pragma unroll
        for (int j = 0; j < 8; j++)
            Po[pobase + (size_t)row * 128 + j * 16 + l16] = f2bf(o[j][r]);
    }
}

// ---------------------------------------------------------------------------
// Combine n_ch(qt) partials per (b,qt). grid (32,8), 256 thr.
// ---------------------------------------------------------------------------
__global__ __launch_bounds__(256)
void combine(const unsigned short* __restrict__ Po, const float* __restrict__ Pm,
             const float* __restrict__ Pl, float* __restrict__ Out)
{
    const int qt = blockIdx.x, b = blockIdx.y;
    const int g = qt >> 2;
    const int n_ch = g + 1;
    const int cbase = 2 * g * (g + 1) + (qt - 4 * g) * (g + 1);
    const int t = threadIdx.x;
    const int col = t & 127, rh = t >> 7;
    const size_t p0 = (size_t)b * NCH + cbase;

    for (int pass = 0; pass < 32; pass++) {
        int row = pass * 2 + rh;
        float m[8], lv[8];
        float ms = -1e30f;
        for (int s = 0; s < n_ch; s++) {
            m[s]  = Pm[(p0 + s) * 64 + row];
            lv[s] = Pl[(p0 + s) * 64 + row];
            ms = fmaxf(ms, m[s]);
        }
        float l = 0.0f, acc = 0.0f;
        for (int s = 0; s < n_ch; s++) {
            float w = exp2f(m[s] - ms);
            l += w * lv[s];
            acc += w * bf2f(Po[(p0 + s) * 8192 + (size_t)row * 128 + col]);
        }
        Out[((size_t)b * SS + qt * 64 + row) * HH + col] = acc / l;
    }
}

extern "C" void kernel_launch(void* const* d_in, const int* in_sizes, int n_in,
                              void* d_out, int out_size, void* d_ws, size_t ws_size,
                              hipStream_t stream) {
    const float* X    = (const float*)d_in[0];
    const float* mask = (const float*)d_in[1];
    const float* Wq   = (const float*)d_in[2];
    const float* Wk   = (const float*)d_in[3];
    const float* Wv   = (const float*)d_in[4];

    char* ws = (char*)d_ws;
    // region A: Xb (25.2 MB) consumed by qkv_gemm, then reused as Po (18.9 MB)
    unsigned short* Xb = (unsigned short*)ws;
    unsigned short* Po = (unsigned short*)ws;
    ws += (size_t)MM * EE * 2;                                   // 25.17 MB
    unsigned short* Wb = (unsigned short*)ws; ws += (size_t)384 * EE * 2;
    unsigned short* Q  = (unsigned short*)ws; ws += (size_t)MM * HH * 2;
    unsigned short* Kb = (unsigned short*)ws; ws += (size_t)MM * HH * 2;
    unsigned short* Vt = (unsigned short*)ws; ws += (size_t)MM * HH * 2;
    float* Pm = (float*)ws; ws += (size_t)BB * NCH * 64 * 4;
    float* Pl = (float*)ws;

    cvt<<<12288 + 288, 256, 0, stream>>>(X, mask, Wq, Wk, Wv, Xb, Wb);
    qkv_gemm<<<dim3(MM / 128, 3), 256, 0, stream>>>(Xb, Wb, Q, Kb, Vt);
    attn<<<dim3(NCH, BB), 256, 0, stream>>>(Q, Kb, Vt, Po, Pm, Pl);
    combine<<<dim3(NQT, BB), 256, 0, stream>>>(Po, Pm, Pl, (float*)d_out);
}

// Round 4
// 177.377 us; speedup vs baseline: 1.6345x; 1.6345x over previous
//
#include <hip/hip_runtime.h>
#include <hip/hip_bf16.h>

// Problem constants: B=8, S=2048, E=768, HEAD=128
#define BB 8
#define SS 2048
#define EE 768
#define HH 128
#define MM (BB*SS)     // 16384
#define NQT 32         // 64-row q-tiles per batch
#define NCH 144        // chunks per batch: sum_{qt} ceil((qt+1)/4)

typedef __attribute__((ext_vector_type(8))) short bf16x8;
typedef __attribute__((ext_vector_type(4))) float f32x4;

__device__ __forceinline__ unsigned short f2bf(float x) {
    unsigned int u = __float_as_uint(x);
    u += 0x7fff + ((u >> 16) & 1);   // RNE
    return (unsigned short)(u >> 16);
}
__device__ __forceinline__ float bf2f(unsigned short h) {
    return __uint_as_float(((unsigned int)h) << 16);
}
// async global->LDS, 16B per lane; LDS dest = wave-uniform base + lane*16
__device__ __forceinline__ void gld16(const unsigned short* g, unsigned short* l) {
    __builtin_amdgcn_global_load_lds(
        (const __attribute__((address_space(1))) unsigned int*)g,
        (__attribute__((address_space(3))) unsigned int*)l, 16, 0, 0);
}

// ---------------------------------------------------------------------------
// cvt: Xb = bf16(X * mask)  [16384][768];  Wb = bf16([Wq;Wk;Wv]) [384][768]
// grid 12288 + 288 blocks, 256 thr
// ---------------------------------------------------------------------------
__global__ __launch_bounds__(256)
void cvt(const float* __restrict__ X, const float* __restrict__ mask,
         const float* __restrict__ Wq, const float* __restrict__ Wk,
         const float* __restrict__ Wv,
         unsigned short* __restrict__ Xb, unsigned short* __restrict__ Wb)
{
    if (blockIdx.x < 12288) {
        size_t i4 = ((size_t)blockIdx.x * 256 + threadIdx.x) * 4;
        int row = (int)(i4 / EE);
        float mk = mask[row];
        float4 v = *(const float4*)(X + i4);
        ushort4 o;
        o.x = f2bf(v.x * mk); o.y = f2bf(v.y * mk);
        o.z = f2bf(v.z * mk); o.w = f2bf(v.w * mk);
        *(ushort4*)(Xb + i4) = o;
    } else {
        int i4 = ((blockIdx.x - 12288) * 256 + threadIdx.x) * 4;   // < 294912
        const float* src; int off;
        if (i4 < 98304)       { src = Wq; off = i4; }
        else if (i4 < 196608) { src = Wk; off = i4 - 98304; }
        else                  { src = Wv; off = i4 - 196608; }
        float4 v = *(const float4*)(src + off);
        ushort4 o;
        o.x = f2bf(v.x); o.y = f2bf(v.y); o.z = f2bf(v.z); o.w = f2bf(v.w);
        *(ushort4*)(Wb + i4) = o;
    }
}

// ---------------------------------------------------------------------------
// QKV GEMM: 128Mx128N tile, BK=64, grid (128, 3), 4 waves 2x2 of 64x64.
// global_load_lds(16B) staging, xor-swizzled unpadded LDS (conflict-free).
// mat 2 (V) epilogue: LDS-bounce transpose -> coalesced Vt[h][token] stores.
// ---------------------------------------------------------------------------
__global__ __launch_bounds__(256, 2)
void qkv_gemm(const unsigned short* __restrict__ Xb, const unsigned short* __restrict__ Wb,
              unsigned short* __restrict__ Q, unsigned short* __restrict__ K,
              unsigned short* __restrict__ Vt)
{
    const int m0  = blockIdx.x * 128;
    const int mat = blockIdx.y;
    const int n0g = mat * 128;               // row offset into Wb [384][768]

    __shared__ __align__(16) unsigned short SM[16384];   // As[0:8192) Bs[8192:16384)
    unsigned short* As = SM;
    unsigned short* Bs = SM + 8192;

    const int t = threadIdx.x, lane = t & 63;
    const int quad = lane >> 4, l16 = lane & 15;
    const int wave = t >> 6;
    const int wm = (wave >> 1) * 64, wn = (wave & 1) * 64;
    const int wub = (t & 192) * 8;           // wave-uniform chunk base *8 shorts

    f32x4 acc[4][4];
#pragma unroll
    for (int i = 0; i < 4; i++)
#pragma unroll
        for (int j = 0; j < 4; j++) acc[i][j] = (f32x4)0.0f;

    for (int k0 = 0; k0 < EE; k0 += 64) {
        __syncthreads();
        // A/B tiles: 128 rows x 8 chunks(16B). slot = c ^ (row&7).
#pragma unroll
        for (int i = 0; i < 4; i++) {
            int cg = i * 256 + t;
            int row = cg >> 3, slot = cg & 7;
            int cc = slot ^ (row & 7);
            gld16(Xb + (size_t)(m0 + row) * EE + k0 + cc * 8, As + i * 2048 + wub);
            gld16(Wb + (size_t)(n0g + row) * EE + k0 + cc * 8, Bs + i * 2048 + wub);
        }
        __syncthreads();
#pragma unroll
        for (int kk = 0; kk < 2; kk++) {
            bf16x8 a[4], b[4];
#pragma unroll
            for (int i = 0; i < 4; i++) {
                int row = wm + i * 16 + l16;
                a[i] = *(const bf16x8*)&As[row * 64 + (((kk * 4 + quad) ^ (l16 & 7)) << 3)];
            }
#pragma unroll
            for (int j = 0; j < 4; j++) {
                int row = wn + j * 16 + l16;
                b[j] = *(const bf16x8*)&Bs[row * 64 + (((kk * 4 + quad) ^ (l16 & 7)) << 3)];
            }
#pragma unroll
            for (int i = 0; i < 4; i++)
#pragma unroll
                for (int j = 0; j < 4; j++)
                    acc[i][j] = __builtin_amdgcn_mfma_f32_16x16x32_bf16(a[i], b[j], acc[i][j], 0, 0, 0);
        }
    }

    if (mat < 2) {
        unsigned short* dst = (mat == 0) ? Q : K;
#pragma unroll
        for (int i = 0; i < 4; i++)
#pragma unroll
            for (int r = 0; r < 4; r++) {
                int m = m0 + wm + i * 16 + quad * 4 + r;
#pragma unroll
                for (int j = 0; j < 4; j++)
                    dst[(size_t)m * HH + wn + j * 16 + l16] = f2bf(acc[i][j][r]);
            }
    } else {
        // transpose 128(tok) x 128(h) through LDS, swizzle slot = c ^ (h&15)
        __syncthreads();
#pragma unroll
        for (int i = 0; i < 4; i++)
#pragma unroll
            for (int r = 0; r < 4; r++) {
                int tok = wm + i * 16 + quad * 4 + r;
                int cc = tok >> 3, w = tok & 7;
#pragma unroll
                for (int j = 0; j < 4; j++) {
                    int h = wn + j * 16 + l16;
                    SM[h * 128 + ((cc ^ (h & 15)) << 3) + w] = f2bf(acc[i][j][r]);
                }
            }
        __syncthreads();
        const int bidx = m0 >> 11, mloc = m0 & 2047;
#pragma unroll
        for (int it = 0; it < 8; it++) {
            int cg = it * 256 + t;
            int h = cg >> 4, cc = cg & 15;
            ulonglong2 v = *(const ulonglong2*)&SM[h * 128 + ((cc ^ (h & 15)) << 3)];
            *(ulonglong2*)&Vt[((size_t)bidx * HH + h) * SS + mloc + cc * 8] = v;
        }
    }
}

// ---------------------------------------------------------------------------
// Flash attention, balanced chunked k-split: chunk id c in [0,144) per batch.
// qt group g = qt>>2 has g+1 chunks of <=4 k-tiles each (contiguous).
// LDS: Ks 16K + Vs 16K + Ps 8K = 40KB -> 4 blocks/CU. All xor-swizzled.
// grid (144, 8), block 256 (4 waves of 16 q-rows)
// ---------------------------------------------------------------------------
__global__ __launch_bounds__(256, 4)
void attn(const unsigned short* __restrict__ Q, const unsigned short* __restrict__ K,
          const unsigned short* __restrict__ Vt,
          unsigned short* __restrict__ Po, float* __restrict__ Pm, float* __restrict__ Pl)
{
    const int b = blockIdx.y;
    const int c = blockIdx.x;
    // decode chunk id -> (qt, ch):  cumulative chunks before group g = 2g(g+1)
    int g = (int)((__builtin_sqrtf(2.0f * c + 1.0f) - 1.0f) * 0.5f);
    while (2 * (g + 1) * (g + 2) <= c) g++;
    while (2 * g * (g + 1) > c) g--;
    const int idx = c - 2 * g * (g + 1);
    const int qt = 4 * g + idx / (g + 1);
    const int ch = idx % (g + 1);
    const int q0 = qt * 64;
    const int kt0 = ch * 4;
    const int kt1 = min(kt0 + 4, qt + 1);

    const int t = threadIdx.x, lane = t & 63;
    const int wave = t >> 6, quad = lane >> 4, l16 = lane & 15;
    const int wub = (t & 192) * 8;

    __shared__ __align__(16) unsigned short Ks[64 * 128];   // [tok][d], slot=c^ (tok&15)
    __shared__ __align__(16) unsigned short Vs[128 * 64];   // [h][tok], slot=c^(h&7)
    __shared__ __align__(16) unsigned short Ps[4][16 * 64]; // per-wave, slot=c^(row&7)

    bf16x8 qf[4];
    {
        const unsigned short* qrow = Q + (size_t)(b * SS + q0 + wave * 16 + l16) * HH;
#pragma unroll
        for (int dd = 0; dd < 4; dd++)
            qf[dd] = *(const bf16x8*)(qrow + dd * 32 + quad * 8);
    }

    f32x4 o[8];
#pragma unroll
    for (int j = 0; j < 8; j++) o[j] = (f32x4)0.0f;
    f32x4 o9 = (f32x4)0.0f;
    float mrow[4];
#pragma unroll
    for (int r = 0; r < 4; r++) mrow[r] = -1e30f;

    const float sscale = 0.08838834764831845f * 1.4426950408889634f;

    bf16x8 ones;
    {
        short e = (l16 == 0) ? (short)0x3F80 : (short)0;
        ones = (bf16x8){e, e, e, e, e, e, e, e};
    }

    for (int kt = kt0; kt < kt1; kt++) {
        const int k0 = kt * 64;
        __syncthreads();
        // K-tile: 64 rows x 16 chunks
#pragma unroll
        for (int i = 0; i < 4; i++) {
            int cg = i * 256 + t;
            int row = cg >> 4, slot = cg & 15;
            int cc = slot ^ (row & 15);
            gld16(K + (size_t)(b * SS + k0 + row) * HH + cc * 8, Ks + i * 2048 + wub);
        }
        // V-tile: 128 rows x 8 chunks
#pragma unroll
        for (int i = 0; i < 4; i++) {
            int cg = i * 256 + t;
            int row = cg >> 3, slot = cg & 7;
            int cc = slot ^ (row & 7);
            gld16(Vt + ((size_t)b * HH + row) * SS + k0 + cc * 8, Vs + i * 2048 + wub);
        }
        __syncthreads();

        // S = Q K^T
        f32x4 s[4];
#pragma unroll
        for (int ct = 0; ct < 4; ct++) s[ct] = (f32x4)0.0f;
#pragma unroll
        for (int dd = 0; dd < 4; dd++) {
#pragma unroll
            for (int ct = 0; ct < 4; ct++) {
                bf16x8 kfr = *(const bf16x8*)&Ks[(ct * 16 + l16) * 128 + (((dd * 4 + quad) ^ l16) << 3)];
                s[ct] = __builtin_amdgcn_mfma_f32_16x16x32_bf16(qf[dd], kfr, s[ct], 0, 0, 0);
            }
        }

        const bool diag = (kt == qt);
        float sv[4][4];
#pragma unroll
        for (int ct = 0; ct < 4; ct++) {
            int col = k0 + ct * 16 + l16;
#pragma unroll
            for (int r = 0; r < 4; r++) {
                float v = s[ct][r] * sscale;
                if (diag) {
                    int row = q0 + wave * 16 + quad * 4 + r;
                    if (col > row) v = -1e30f;
                }
                sv[ct][r] = v;
            }
        }

        float alpha[4];
#pragma unroll
        for (int r = 0; r < 4; r++) {
            float v = fmaxf(fmaxf(sv[0][r], sv[1][r]), fmaxf(sv[2][r], sv[3][r]));
            v = fmaxf(v, __shfl_xor(v, 1));
            v = fmaxf(v, __shfl_xor(v, 2));
            v = fmaxf(v, __shfl_xor(v, 4));
            v = fmaxf(v, __shfl_xor(v, 8));
            float mnew = fmaxf(mrow[r], v);
            alpha[r] = exp2f(mrow[r] - mnew);
            mrow[r]  = mnew;
        }
        // P -> wave-private swizzled LDS (row = quad*4+r, col = ct*16+l16)
#pragma unroll
        for (int ct = 0; ct < 4; ct++) {
#pragma unroll
            for (int r = 0; r < 4; r++) {
                float p = exp2f(sv[ct][r] - mrow[r]);
                int row = quad * 4 + r, col = ct * 16 + l16;
                int cc = col >> 3;
                Ps[wave][row * 64 + (((cc ^ (row & 7)) << 3) | (col & 7))] = f2bf(p);
            }
        }
#pragma unroll
        for (int j = 0; j < 8; j++)
#pragma unroll
            for (int r = 0; r < 4; r++) o[j][r] *= alpha[r];
#pragma unroll
        for (int r = 0; r < 4; r++) o9[r] *= alpha[r];

        // PV + row-sum column
#pragma unroll
        for (int kk = 0; kk < 2; kk++) {
            bf16x8 pf = *(const bf16x8*)&Ps[wave][l16 * 64 + (((kk * 4 + quad) ^ (l16 & 7)) << 3)];
#pragma unroll
            for (int j = 0; j < 8; j++) {
                bf16x8 vf = *(const bf16x8*)&Vs[(j * 16 + l16) * 64 + (((kk * 4 + quad) ^ (l16 & 7)) << 3)];
                o[j] = __builtin_amdgcn_mfma_f32_16x16x32_bf16(pf, vf, o[j], 0, 0, 0);
            }
            o9 = __builtin_amdgcn_mfma_f32_16x16x32_bf16(pf, ones, o9, 0, 0, 0);
        }
    }

    const size_t pidx = (size_t)b * NCH + c;
    const size_t pobase = pidx * (64 * 128);
    const size_t mbase  = pidx * 64;
#pragma unroll
    for (int r = 0; r < 4; r++) {
        int row = wave * 16 + quad * 4 + r;
        if (l16 == 0) { Pm[mbase + row] = mrow[r]; Pl[mbase + row] = o9[r]; }
#pragma unroll
        for (int j = 0; j < 8; j++)
            Po[pobase + (size_t)row * 128 + j * 16 + l16] = f2bf(o[j][r]);
    }
}

// ---------------------------------------------------------------------------
// Combine n_ch(qt) partials per (b,qt). grid (32, 8, 4): each block does 16
// q-rows. Weights precomputed into LDS (no private arrays -> no scratch);
// accumulation fully unrolled to 8 with zero-weight predication for ILP.
// ---------------------------------------------------------------------------
__global__ __launch_bounds__(256)
void combine(const unsigned short* __restrict__ Po, const float* __restrict__ Pm,
             const float* __restrict__ Pl, float* __restrict__ Out)
{
    const int qt = blockIdx.x, b = blockIdx.y, qr = blockIdx.z;  // 16-row quarter
    const int g = qt >> 2;
    const int n_ch = g + 1;
    const int cbase = 2 * g * (g + 1) + (qt - 4 * g) * (g + 1);
    const size_t p0 = (size_t)b * NCH + cbase;
    const int t = threadIdx.x, col = t & 127, rh = t >> 7;

    __shared__ float sm[8][16], sl[8][16], sw[8][16];
    __shared__ float sinv[16];

    if (t < 128) {
        int s = t >> 4, row = t & 15;
        float mv = -1e30f, lv = 0.0f;
        if (s < n_ch) {
            mv = Pm[(p0 + s) * 64 + qr * 16 + row];
            lv = Pl[(p0 + s) * 64 + qr * 16 + row];
        }
        sm[s][row] = mv; sl[s][row] = lv;
    }
    __syncthreads();
    if (t < 16) {
        int row = t;
        float ms = sm[0][row];
#pragma unroll
        for (int s = 1; s < 8; s++) ms = fmaxf(ms, sm[s][row]);
        float l = 0.0f;
#pragma unroll
        for (int s = 0; s < 8; s++) {
            float w = (sm[s][row] > -1e29f) ? exp2f(sm[s][row] - ms) : 0.0f;
            sw[s][row] = w;
            l += w * sl[s][row];
        }
        sinv[row] = 1.0f / l;
    }
    __syncthreads();

#pragma unroll
    for (int pass = 0; pass < 8; pass++) {
        int row = pass * 2 + rh;          // 0..15 local
        int grow = qr * 16 + row;         // 0..63 within q-tile
        float acc = 0.0f;
#pragma unroll
        for (int s = 0; s < 8; s++) {
            int ss = (s < n_ch) ? s : 0;  // keep load valid; weight is 0
            acc += sw[s][row] * bf2f(Po[(p0 + ss) * 8192 + (size_t)grow * 128 + col]);
        }
        Out[((size_t)b * SS + qt * 64 + grow) * HH + col] = acc * sinv[row];
    }
}

extern "C" void kernel_launch(void* const* d_in, const int* in_sizes, int n_in,
                              void* d_out, int out_size, void* d_ws, size_t ws_size,
                              hipStream_t stream) {
    const float* X    = (const float*)d_in[0];
    const float* mask = (const float*)d_in[1];
    const float* Wq   = (const float*)d_in[2];
    const float* Wk   = (const float*)d_in[3];
    const float* Wv   = (const float*)d_in[4];

    char* ws = (char*)d_ws;
    // region A: Xb (25.2 MB) consumed by qkv_gemm, then reused as Po (18.9 MB)
    unsigned short* Xb = (unsigned short*)ws;
    unsigned short* Po = (unsigned short*)ws;
    ws += (size_t)MM * EE * 2;                                   // 25.17 MB
    unsigned short* Wb = (unsigned short*)ws; ws += (size_t)384 * EE * 2;
    unsigned short* Q  = (unsigned short*)ws; ws += (size_t)MM * HH * 2;
    unsigned short* Kb = (unsigned short*)ws; ws += (size_t)MM * HH * 2;
    unsigned short* Vt = (unsigned short*)ws; ws += (size_t)MM * HH * 2;
    float* Pm = (float*)ws; ws += (size_t)BB * NCH * 64 * 4;
    float* Pl = (float*)ws;

    cvt<<<12288 + 288, 256, 0, stream>>>(X, mask, Wq, Wk, Wv, Xb, Wb);
    qkv_gemm<<<dim3(MM / 128, 3), 256, 0, stream>>>(Xb, Wb, Q, Kb, Vt);
    attn<<<dim3(NCH, BB), 256, 0, stream>>>(Q, Kb, Vt, Po, Pm, Pl);
    combine<<<dim3(NQT, BB, 4), 256, 0, stream>>>(Po, Pm, Pl, (float*)d_out);
}